// Round 3
// baseline (1717.711 us; speedup 1.0000x reference)
//
#include <hip/hip_runtime.h>
#include <math.h>

// BiCGStab, 8 independent 512x512 images, single persistent kernel.
// 256 blocks x 512 threads (PLAIN launch; min-capacity 1 block/CU => all
// 256 blocks always co-resident => custom barriers are deadlock-free).
// Block = 16 rows of one image (thread = 1 column). Per-image atomic
// barriers (32 blocks); scalars recomputed redundantly per block from
// fixed-order reductions (bit-identical -> uniform branches).

namespace {

constexpr int NIMG = 8;
constexpr int NSd  = 512;
constexpr int S    = NSd*NSd;          // 262144
constexpr int NSF  = NIMG*S;           // plane stride (floats)
constexpr int PADS = 514;
constexpr int NB   = 256;              // blocks
constexpr int IPB  = 32;               // blocks per image
constexpr int RPB  = 16;               // rows per block
constexpr int NT   = 512;              // threads per block
constexpr float EPSF = 1e-9f;
constexpr float THR  = 1e-9f * 262144.0f;
constexpr float RX_  = 50.0f, RY_ = 50.0f, RXX_ = 100.0f, RYY_ = 100.0f;

// plane layout in ws
enum { P_CA=0, P_CB, P_X, P_R, P_P0, P_P1, P_V0, P_V1, NPL };
// aux (floats) after NPL planes
constexpr int A_PA=0, A_PB=256, A_PC=512, A_MEANP=768, A_BAR=1024; // BAR: 8*32 uints

__device__ __forceinline__ int cl(int i){ return i<0?0:(i>NSd-1?NSd-1:i); }

__device__ __forceinline__ void img_barrier(unsigned* bar, unsigned target){
  __syncthreads();                 // drains each wave's stores to L2
  if (threadIdx.x == 0){
    __hip_atomic_fetch_add(bar, 1u, __ATOMIC_RELEASE, __HIP_MEMORY_SCOPE_AGENT);
    while (__hip_atomic_load(bar, __ATOMIC_RELAXED, __HIP_MEMORY_SCOPE_AGENT) < target)
      __builtin_amdgcn_s_sleep(2);
    __threadfence();               // acquire: invalidate CU L1 + XCD L2
  }
  __syncthreads();
}

// sum of arr[img*32 .. +31], identical value in all threads (fixed order)
__device__ __forceinline__ float img_red1(const float* arr, int img){
  __shared__ float bc1;
  if (threadIdx.x < 32){
    float a = arr[img*IPB + threadIdx.x];
    #pragma unroll
    for (int o=16;o;o>>=1) a += __shfl_xor(a,o);
    if (threadIdx.x==0) bc1 = a;
  }
  __syncthreads();
  float v = bc1;
  __syncthreads();
  return v;
}

// reduce n (<=3) partial arrays (PA,PB,PC) for one image
__device__ __forceinline__ void img_red3(const float* aux, int img, int n, float* out){
  __shared__ float bc[3];
  int w = threadIdx.x >> 6, l = threadIdx.x & 63;
  if (w < n && l < 32){
    const float* arr = aux + w*NB;
    float a = arr[img*IPB + l];
    #pragma unroll
    for (int o=16;o;o>>=1) a += __shfl_xor(a,o);
    if (!l) bc[w] = a;
  }
  __syncthreads();
  #pragma unroll
  for (int i=0;i<3;++i) if (i<n) out[i] = bc[i];
  __syncthreads();
}

// block-reduce 3 values -> one slot each (thread 0 writes); fixed order
__device__ __forceinline__ void store3(float a, float b, float c2,
                                       float* pa, float* pb, float* pc){
  #pragma unroll
  for (int o=32;o;o>>=1){ a+=__shfl_xor(a,o); b+=__shfl_xor(b,o); c2+=__shfl_xor(c2,o); }
  __shared__ float sa[8], sb[8], sc[8];
  int w = threadIdx.x>>6;
  if ((threadIdx.x&63)==0){ sa[w]=a; sb[w]=b; sc[w]=c2; }
  __syncthreads();
  if (threadIdx.x==0){
    float ta=0.f, tb=0.f, tc=0.f;
    #pragma unroll
    for (int i=0;i<8;++i){ ta+=sa[i]; tb+=sb[i]; tc+=sc[i]; }
    *pa=ta; *pb=tb; *pc=tc;
  }
  __syncthreads();
}

// A(z) from LDS tile (rows y0-1..y0+16 clamped), coefs rebuilt from CA/CB
__device__ __forceinline__ float applyA_tile(const float (*tile)[NSd],
    const float* __restrict__ CA, const float* __restrict__ CB,
    int bS, int fy, int rr, int col){
  float zc  = tile[rr+1][col];
  float zxm = tile[rr+1][col>0      ? col-1 : col];
  float zxp = tile[rr+1][col<NSd-1  ? col+1 : col];
  float zym = tile[rr  ][col];
  float zyp = tile[rr+2][col];
  int o = bS + (fy<<9) + col;
  float ax  = CA[o];
  float axm = (col>0) ? CA[o-1]   : 0.f;
  float by  = CB[o];
  float bym = (fy>0)  ? CB[o-NSd] : 0.f;
  float boo = 1.f + 2.f*(RXX_+RYY_) + ax - axm + by - bym;
  return boo*zc + (-RXX_-axm)*zxm + (-RYY_-bym)*zym
       + (-RYY_+by)*zyp + (-RXX_+ax)*zxp;
}

// A(z) straight from a global plane (restart path: A(x))
__device__ __forceinline__ float applyA_glob(const float* __restrict__ Z,
    const float* __restrict__ CA, const float* __restrict__ CB,
    int bS, int fy, int col){
  int ro = bS + (fy<<9);
  float zc  = Z[ro+col];
  float zxm = Z[ro+cl(col-1)];
  float zxp = Z[ro+cl(col+1)];
  float zym = Z[bS+(cl(fy-1)<<9)+col];
  float zyp = Z[bS+(cl(fy+1)<<9)+col];
  float ax  = CA[ro+col];
  float axm = (col>0) ? CA[ro+col-1]   : 0.f;
  float by  = CB[ro+col];
  float bym = (fy>0)  ? CB[ro-NSd+col] : 0.f;
  float boo = 1.f + 2.f*(RXX_+RYY_) + ax - axm + by - bym;
  return boo*zc + (-RXX_-axm)*zxm + (-RYY_-bym)*zym
       + (-RYY_+by)*zyp + (-RXX_+ax)*zxp;
}

__global__ void __launch_bounds__(NT, 2) solve(const float* __restrict__ Vg,
    const float* __restrict__ M1g, const float* __restrict__ M2g,
    const int* __restrict__ kmp, float* __restrict__ outg, float* __restrict__ ws){
  __shared__ float tile[RPB+2][NSd];   // 18*512*4 = 36864 B
  const int tid = threadIdx.x, blk = blockIdx.x;
  const int img = blk >> 5, sub = blk & (IPB-1);
  const int y0 = sub * RPB, bS = img * S;
  float* CA = ws + (size_t)P_CA*NSF;
  float* CB = ws + (size_t)P_CB*NSF;
  float* Xx = ws + (size_t)P_X*NSF;
  float* Rr = ws + (size_t)P_R*NSF;
  float* aux = ws + (size_t)NPL*NSF;
  unsigned* bar = (unsigned*)(aux + A_BAR) + img*32;
  unsigned ep = 0;
  const int kmax = kmp[0];
  int ppar = 0, vpar = 0;

  // ---- S1: mean partials ----
  {
    float ms = 0.f;
    #pragma unroll
    for (int rr=0; rr<RPB; ++rr) ms += Vg[bS + ((y0+rr)<<9) + tid];
    store3(ms, 0.f, 0.f, &aux[A_MEANP+blk], &aux[A_PB+blk], &aux[A_PC+blk]);
  }
  img_barrier(bar, IPB*(++ep));
  const float c = img_red1(aux + A_MEANP, img) * (1.0f/262144.0f);

  // ---- S2: coefficient planes + init (x=c, p=r=r0=b-A(x0)) ----
  float r0_reg[RPB], t_reg[RPB];
  {
    float* Pc = ws + (size_t)(P_P0+ppar)*NSF;
    float pa = 0.f;
    #pragma unroll
    for (int rr=0; rr<RPB; ++rr){
      int fy = y0+rr, ro = bS+(fy<<9), o = ro+tid;
      float vc  = Vg[o];
      float vxp = Vg[ro+cl(tid+1)], vxm = Vg[ro+cl(tid-1)];
      float vyp = Vg[bS+(cl(fy+1)<<9)+tid], vym = Vg[bS+(cl(fy-1)<<9)+tid];
      float m1c = M1g[o], m1m = M1g[ro+cl(tid-1)];
      float m2c = M2g[o], m2m = M2g[bS+(cl(fy-1)<<9)+tid];
      float d1x  = (vxp-vc)/(0.5f*(vxp+vc))*m1c;
      float d1xm = (vc-vxm)/(0.5f*(vc+vxm))*m1m;
      float d2y  = (vyp-vc)/(0.5f*(vyp+vc))*m2c;
      float d2ym = (vc-vym)/(0.5f*(vc+vym))*m2m;
      CA[o] = RX_*d1x; CB[o] = RY_*d2y;
      float boo = 1.f+2.f*(RXX_+RYY_) - RX_*(d1xm-d1x) - RY_*(d2ym-d2y);
      float bxp = -RXX_+RX_*d1x, bxm = -RXX_-RX_*d1xm;
      float byp = -RYY_+RY_*d2y, bym = -RYY_-RY_*d2ym;
      float val = boo*c + bxm*c + bym*c + byp*c + bxp*c;
      float pn = c - val;
      Xx[o]=c; Pc[o]=pn; Rr[o]=pn; r0_reg[rr]=pn;
      pa += pn*pn;
    }
    store3(pa, 0.f, 0.f, &aux[A_PA+blk], &aux[A_PB+blk], &aux[A_PC+blk]);
  }
  img_barrier(bar, IPB*(++ep));
  float rr0 = img_red1(aux + A_PA, img);
  float r0abs = sqrtf(rr0), rabs = r0abs;
  int kcnt = 0;
  bool c4p = false;
  float alpha = 0.f, omega = 0.f, beta = 0.f;
  float red[3];

  for (int it=0; it<kmax; ++it){
    if (!((kcnt < kmax) && (rabs > THR))) break;
    float* Pold = ws + (size_t)(P_P0+ppar)*NSF;
    float* Pnew = ws + (size_t)(P_P0+(ppar^1))*NSF;
    float* Vold = ws + (size_t)(P_V0+vpar)*NSF;
    float* Vnew = ws + (size_t)(P_V0+(vpar^1))*NSF;

    // ---- P1: (deferred p-update) ; v = A(p) ; partials <v,r0>, <v,v> ----
    if (c4p){
      for (int st=0; st<RPB+2; ++st){
        int fy = cl(y0-1+st), o = bS+(fy<<9)+tid;
        tile[st][tid] = Rr[o] + beta*(Pold[o] - omega*Vold[o]);
      }
    } else {
      for (int st=0; st<RPB+2; ++st){
        int fy = cl(y0-1+st);
        tile[st][tid] = Pold[bS+(fy<<9)+tid];
      }
    }
    __syncthreads();
    {
      float s1=0.f, s2=0.f;
      #pragma unroll
      for (int rr=0; rr<RPB; ++rr){
        int fy = y0+rr, o = bS+(fy<<9)+tid;
        if (c4p) Pnew[o] = tile[rr+1][tid];
        float val = applyA_tile(tile, CA, CB, bS, fy, rr, tid);
        Vnew[o] = val;
        s1 += val*r0_reg[rr]; s2 += val*val;
      }
      store3(s1, s2, 0.f, &aux[A_PA+blk], &aux[A_PB+blk], &aux[A_PC+blk]);
    }
    if (c4p) ppar ^= 1;
    vpar ^= 1;
    img_barrier(bar, IPB*(++ep));
    float* Pc = ws + (size_t)(P_P0+ppar)*NSF;
    float* Vc = ws + (size_t)(P_V0+vpar)*NSF;
    img_red3(aux, img, 2, red);
    float sig = red[0], vabs = sqrtf(red[1]);
    bool res = (sig <= EPSF*vabs*r0abs);

    if (res){
      // ---- restart: p = r = r0 = b - A(x) ----
      float* Pw = ws + (size_t)(P_P0+(ppar^1))*NSF;
      float pa = 0.f;
      #pragma unroll
      for (int rr=0; rr<RPB; ++rr){
        int fy = y0+rr, o = bS+(fy<<9)+tid;
        float pn = c - applyA_glob(Xx, CA, CB, bS, fy, tid);
        Pw[o]=pn; Rr[o]=pn; r0_reg[rr]=pn;
        pa += pn*pn;
      }
      ppar ^= 1;
      store3(pa, 0.f, 0.f, &aux[A_PA+blk], &aux[A_PB+blk], &aux[A_PC+blk]);
      img_barrier(bar, IPB*(++ep));
      rr0 = img_red1(aux + A_PA, img);
      r0abs = sqrtf(rr0); rabs = r0abs; kcnt++;
      c4p = false;
      continue;
    }

    // ---- P2: s = r - alpha*v (LDS, 18 rows); t = A(s) (regs) ----
    alpha = rr0 / sig;
    {
      float ssp = 0.f;
      for (int st=0; st<RPB+2; ++st){
        int fy = cl(y0-1+st), o = bS+(fy<<9)+tid;
        float sv = Rr[o] - alpha*Vc[o];
        tile[st][tid] = sv;
        if (st>=1 && st<=RPB) ssp += sv*sv;
      }
      __syncthreads();
      float tsp=0.f, ttp=0.f;
      #pragma unroll
      for (int rr=0; rr<RPB; ++rr){
        int fy = y0+rr;
        float tv = applyA_tile(tile, CA, CB, bS, fy, rr, tid);
        t_reg[rr] = tv;
        tsp += tv*tile[rr+1][tid];
        ttp += tv*tv;
      }
      store3(ssp, tsp, ttp, &aux[A_PA+blk], &aux[A_PB+blk], &aux[A_PC+blk]);
    }
    img_barrier(bar, IPB*(++ep));
    img_red3(aux, img, 3, red);
    float snorm = sqrtf(red[0]);

    if (snorm <= THR){
      // ---- c3: x += alpha*p ; r = s ----
      #pragma unroll
      for (int rr=0; rr<RPB; ++rr){
        int o = bS+((y0+rr)<<9)+tid;
        Xx[o] = Xx[o] + alpha*Pc[o];
        Rr[o] = tile[rr+1][tid];
      }
      rabs = snorm; kcnt++; c4p = false;
      img_barrier(bar, IPB*(++ep));   // x complete before pack
      continue;                        // conv false next iter -> break
    }

    // ---- c4: x += alpha*p + omega*s ; r = s - omega*t ----
    omega = red[1]/red[2];
    {
      float s1=0.f, s2=0.f;
      #pragma unroll
      for (int rr=0; rr<RPB; ++rr){
        int o = bS+((y0+rr)<<9)+tid;
        float sv = tile[rr+1][tid];
        Xx[o] = Xx[o] + alpha*Pc[o] + omega*sv;
        float rn = sv - omega*t_reg[rr];
        Rr[o] = rn;
        s1 += rn*r0_reg[rr]; s2 += rn*rn;
      }
      store3(s1, s2, 0.f, &aux[A_PA+blk], &aux[A_PB+blk], &aux[A_PC+blk]);
    }
    img_barrier(bar, IPB*(++ep));
    img_red3(aux, img, 2, red);
    beta = alpha/omega*(red[0]/rr0);
    rr0 = red[0]; rabs = sqrtf(red[1]); kcnt++;
    c4p = true;
  }

  // ---- pack: out[img][i][j] = (border ? c : x[j-1][i-1]) ----
  float* outb = outg + (size_t)img*PADS*PADS;
  if (sub == 0){
    for (int e = tid; e < 2052; e += NT){
      int i, j;
      if (e < 514)      { i=0;          j=e;        }
      else if (e < 1028){ i=513;        j=e-514;    }
      else if (e < 1540){ i=e-1028+1;   j=0;        }
      else              { i=e-1540+1;   j=513;      }
      outb[i*PADS+j] = c;
    }
  }
  {
    float (*ldst)[65] = (float(*)[65])(&tile[0][0]);   // 64*65*4 = 16640 B
    for (int half=0; half<2; ++half){
      int tt = sub + half*IPB;            // 0..63 tile id
      int r0t = (tt>>3)*64, c0t = (tt&7)*64;
      __syncthreads();
      for (int pass=0; pass<8; ++pass){   // 8*512 = 4096 = 64*64
        int idx = pass*NT + tid;
        int a = idx>>6, b = idx&63;
        ldst[a][b] = Xx[bS + ((r0t+a)<<9) + (c0t+b)];
      }
      __syncthreads();
      for (int pass=0; pass<8; ++pass){
        int idx = pass*NT + tid;
        int b2 = idx>>6, a2 = idx&63;
        outb[(size_t)(c0t+1+b2)*PADS + (r0t+1+a2)] = ldst[a2][b2];
      }
    }
  }
}

} // namespace

extern "C" void kernel_launch(void* const* d_in, const int* in_sizes, int n_in,
                              void* d_out, int out_size, void* d_ws, size_t ws_size,
                              hipStream_t stream){
  const float* V  = (const float*)d_in[0];
  const float* M1 = (const float*)d_in[1];
  const float* M2 = (const float*)d_in[2];
  const int*   km = (const int*)d_in[3];
  float* ws  = (float*)d_ws;
  float* out = (float*)d_out;

  size_t need = ((size_t)NPL*NSF + 4096)*sizeof(float);
  if (ws_size < need) return;

  // zero the per-image barrier counters (graph-capturable)
  hipMemsetAsync((char*)d_ws + ((size_t)NPL*NSF + A_BAR)*sizeof(float),
                 0, 8*32*sizeof(unsigned), stream);

  solve<<<dim3(NB), dim3(NT), 0, stream>>>(V, M1, M2, km, out, ws);
}

// Round 4
// 795.536 us; speedup vs baseline: 2.1592x; 2.1592x over previous
//
#include <hip/hip_runtime.h>
#include <math.h>

// BiCGStab, 8 independent 512x512 images, single persistent kernel.
// 256 blocks x 512 threads (plain launch, 1+ block/CU guaranteed resident).
// img = blk & 7  -> all 32 blocks of an image on one XCD (L2 locality).
// Block = 16 rows; thread = 4 rows x 4 cols. All fields (x,p,r,r0,v,t) in
// registers; global traffic = coefficient planes (L2-resident) + 1-row halo
// exchanges. Scalars recomputed redundantly per block from fixed-order
// reductions (bit-identical -> uniform branches).

namespace {

constexpr int NIMG = 8;
constexpr int NSd  = 512;
constexpr int S    = NSd*NSd;
constexpr int NSF  = NIMG*S;
constexpr int PADS = 514;
constexpr int NB   = 256;
constexpr int IPB  = 32;     // blocks per image
constexpr int RPB  = 16;     // rows per block
constexpr int NT   = 512;
constexpr float EPSF = 1e-9f;
constexpr float THR  = 1e-9f * 262144.0f;
constexpr float RX_=50.f, RY_=50.f, RXX_=100.f, RYY_=100.f;
constexpr float BOO0 = 1.f + 2.f*(RXX_+RYY_);

// global planes in ws
enum { P_CA=0, P_CB, P_PH0, P_PH1, P_VH0, P_VH1, P_RH, P_XH, NPL };
constexpr int A_PA=0, A_PB=256, A_PC=512, A_BAR=768;   // floats after planes

__device__ __forceinline__ int cl(int i){ return i<0?0:(i>NSd-1?NSd-1:i); }

#define LD4(d, p) { float4 _t4 = *reinterpret_cast<const float4*>(p); \
  (d)[0]=_t4.x; (d)[1]=_t4.y; (d)[2]=_t4.z; (d)[3]=_t4.w; }
#define ST4(p, s) { *reinterpret_cast<float4*>(p) = \
  make_float4((s)[0],(s)[1],(s)[2],(s)[3]); }
#define CP4(d, s) { (d)[0]=(s)[0]; (d)[1]=(s)[1]; (d)[2]=(s)[2]; (d)[3]=(s)[3]; }

__device__ __forceinline__ void img_barrier(unsigned* bar, unsigned target){
  __syncthreads();
  if (threadIdx.x == 0){
    __hip_atomic_fetch_add(bar, 1u, __ATOMIC_RELEASE, __HIP_MEMORY_SCOPE_AGENT);
    while (__hip_atomic_load(bar, __ATOMIC_RELAXED, __HIP_MEMORY_SCOPE_AGENT) < target)
      __builtin_amdgcn_s_sleep(1);
    __threadfence();
  }
  __syncthreads();
}

// sum of this image's 32 partials in fixed order; identical in all threads
__device__ __forceinline__ float img_red1(const float* arr, int img){
  __shared__ float bc1;
  if (threadIdx.x < 32){
    float a = arr[img + (threadIdx.x<<3)];
    #pragma unroll
    for (int o=16;o;o>>=1) a += __shfl_xor(a,o);
    if (threadIdx.x==0) bc1 = a;
  }
  __syncthreads();
  float v = bc1;
  __syncthreads();
  return v;
}

__device__ __forceinline__ void img_red3(const float* aux, int img, int n, float* out){
  __shared__ float bc[3];
  int w = threadIdx.x >> 6, l = threadIdx.x & 63;
  if (w < n && l < 32){
    const float* arr = aux + w*NB;
    float a = arr[img + (l<<3)];
    #pragma unroll
    for (int o=16;o;o>>=1) a += __shfl_xor(a,o);
    if (!l) bc[w] = a;
  }
  __syncthreads();
  #pragma unroll
  for (int i=0;i<3;++i) if (i<n) out[i] = bc[i];
  __syncthreads();
}

__device__ __forceinline__ void store3(float* aux, float a, float b, float c2, int blk){
  #pragma unroll
  for (int o=32;o;o>>=1){ a+=__shfl_xor(a,o); b+=__shfl_xor(b,o); c2+=__shfl_xor(c2,o); }
  __shared__ float sa[8], sb[8], sc[8];
  int w = threadIdx.x>>6;
  if ((threadIdx.x&63)==0){ sa[w]=a; sb[w]=b; sc[w]=c2; }
  __syncthreads();
  if (threadIdx.x==0){
    float ta=0.f, tb=0.f, tc=0.f;
    #pragma unroll
    for (int i=0;i<8;++i){ ta+=sa[i]; tb+=sb[i]; tc+=sc[i]; }
    aux[A_PA+blk]=ta; aux[A_PB+blk]=tb; aux[A_PC+blk]=tc;
  }
  __syncthreads();
}

// 5-point stencil on a 4-wide strip; reference summation order preserved
__device__ __forceinline__ void stencil4(const float zc[4], float zl, float zr,
    const float zu[4], const float zd[4],
    const float ax[4], float axl, const float by[4], const float bym[4],
    float out[4]){
  #pragma unroll
  for (int j=0;j<4;++j){
    float axm = j ? ax[j-1] : axl;
    float zxm = j ? zc[j-1] : zl;
    float zxp = (j<3) ? zc[j+1] : zr;
    float boo = BOO0 + ax[j] - axm + by[j] - bym[j];
    out[j] = boo*zc[j] + (-RXX_-axm)*zxm + (-RYY_-bym[j])*zu[j]
           + (-RYY_+by[j])*zd[j] + (-RXX_+ax[j])*zxp;
  }
}

__device__ __forceinline__ void load_coefs(const float* __restrict__ CA,
    const float* __restrict__ CB, int bS, int fy, int c4o,
    float ax[4], float& axl, float by[4], float bym[4]){
  int ro = bS + (fy<<9);
  LD4(ax, CA+ro+c4o);
  axl = c4o ? CA[ro+c4o-1] : 0.f;
  LD4(by, CB+ro+c4o);
  if (fy > 0){ LD4(bym, CB+ro-NSd+c4o); }
  else { bym[0]=0.f; bym[1]=0.f; bym[2]=0.f; bym[3]=0.f; }
}

__global__ void __launch_bounds__(NT, 2) solve(const float* __restrict__ Vg,
    const float* __restrict__ M1g, const float* __restrict__ M2g,
    const int* __restrict__ kmp, float* __restrict__ outg, float* __restrict__ ws){
  __shared__ float tile[RPB+2][NSd];     // 36864 B; reused as [16][516] at pack
  const int tid = threadIdx.x, blk = blockIdx.x;
  const int img = blk & 7, sub = blk >> 3;     // img = blk%8 -> XCD-local image
  const int y0 = sub*RPB, bS = img*S;
  const int cg = tid & 127, r0b = tid >> 7, c4o = cg*4;
  float* CA = ws + (size_t)P_CA*NSF;
  float* CB = ws + (size_t)P_CB*NSF;
  float* RH = ws + (size_t)P_RH*NSF;
  float* XH = ws + (size_t)P_XH*NSF;
  float* aux = ws + (size_t)NPL*NSF;
  unsigned* bar = (unsigned*)(aux + A_BAR) + img*32;
  unsigned ep = 0;
  const int kmax = kmp[0];
  int ppar = 0, vpar = 0;
  const int row0o = bS + (y0<<9) + c4o;            // row y0 offset
  const int row15o = bS + ((y0+15)<<9) + c4o;      // row y0+15 offset

  // ---- setup: coefficient planes + mean partial ----
  {
    float msum = 0.f;
    #pragma unroll
    for (int k=0;k<4;++k){
      int fy = y0 + r0b + 4*k, ro = bS + (fy<<9);
      float vc[4], vd[4], m1[4], m2[4], ca[4], cb[4];
      LD4(vc, Vg+ro+c4o);
      float vr = Vg[ro + (c4o<508 ? c4o+4 : 511)];
      LD4(vd, Vg + bS + (cl(fy+1)<<9) + c4o);
      LD4(m1, M1g+ro+c4o);
      LD4(m2, M2g+ro+c4o);
      #pragma unroll
      for (int j=0;j<4;++j){
        float vn = (j<3) ? vc[j+1] : vr;
        ca[j] = RX_*((vn-vc[j])/(0.5f*(vn+vc[j])))*m1[j];
        cb[j] = RY_*((vd[j]-vc[j])/(0.5f*(vd[j]+vc[j])))*m2[j];
        msum += vc[j];
      }
      ST4(CA+ro+c4o, ca);
      ST4(CB+ro+c4o, cb);
    }
    store3(aux, msum, 0.f, 0.f, blk);
  }
  img_barrier(bar, IPB*(++ep));
  const float c = img_red1(aux+A_PA, img) * (1.0f/262144.0f);

  // ---- init: x=c, p=r=r0 = b - A(c) = -2c(ax-axm+by-bym) ----
  float x_[4][4], p_[4][4], r_[4][4], r0_[4][4], v_[4][4], t_[4][4];
  {
    float* PH0 = ws + (size_t)P_PH0*NSF;
    float pa = 0.f;
    #pragma unroll
    for (int k=0;k<4;++k){
      int fy = y0 + r0b + 4*k;
      float ax[4], axl, by[4], bym[4], pn[4];
      load_coefs(CA, CB, bS, fy, c4o, ax, axl, by, bym);
      #pragma unroll
      for (int j=0;j<4;++j){
        float axm = j ? ax[j-1] : axl;
        pn[j] = -2.f*c*(ax[j]-axm+by[j]-bym[j]);
        x_[k][j]=c; p_[k][j]=pn[j]; r_[k][j]=pn[j]; r0_[k][j]=pn[j];
        pa += pn[j]*pn[j];
        v_[k][j]=0.f; t_[k][j]=0.f;
      }
      if (r0b==0 && k==0){
        float cc[4]={c,c,c,c};
        ST4(PH0+row0o, pn); ST4(RH+row0o, pn); ST4(XH+row0o, cc);
      }
      if (r0b==3 && k==3){
        float cc[4]={c,c,c,c};
        ST4(PH0+row15o, pn); ST4(RH+row15o, pn); ST4(XH+row15o, cc);
      }
    }
    store3(aux, pa, 0.f, 0.f, blk);
  }
  img_barrier(bar, IPB*(++ep));
  float rr0 = img_red1(aux+A_PA, img);
  float r0abs = sqrtf(rr0), rabs = r0abs;
  int kcnt = 0;
  bool c4p = false;
  float alpha=0.f, omega=0.f, beta=0.f;
  float red[3];

  for (int it=0; it<kmax; ++it){
    if (!((kcnt < kmax) && (rabs > THR))) break;
    float* PHo = ws + (size_t)(P_PH0+ppar)*NSF;
    float* PHn = ws + (size_t)(P_PH0+(ppar^1))*NSF;
    float* VHo = ws + (size_t)(P_VH0+vpar)*NSF;
    float* VHn = ws + (size_t)(P_VH0+(vpar^1))*NSF;

    // ---- P1: deferred p-update; v = A(p); partials <v,r0>, <v,v> ----
    float pv0[4], pv3[4];
    #pragma unroll
    for (int k=0;k<4;++k){
      int st = r0b + 4*k + 1;
      float pv[4];
      #pragma unroll
      for (int j=0;j<4;++j){
        pv[j] = c4p ? (r_[k][j] + beta*(p_[k][j]-omega*v_[k][j])) : p_[k][j];
        p_[k][j] = pv[j];
      }
      ST4(&tile[st][c4o], pv);
      if (k==0){ CP4(pv0, pv); }
      if (k==3){ CP4(pv3, pv); }
    }
    if (r0b==0){
      float hv[4];
      if (sub==0){ CP4(hv, pv0); }
      else {
        int hro = bS + ((y0-1)<<9) + c4o;
        if (c4p){
          float rh[4], ph[4], vh[4];
          LD4(rh, RH+hro); LD4(ph, PHo+hro); LD4(vh, VHo+hro);
          #pragma unroll
          for (int j=0;j<4;++j) hv[j] = rh[j] + beta*(ph[j]-omega*vh[j]);
        } else { LD4(hv, PHo+hro); }
      }
      ST4(&tile[0][c4o], hv);
    }
    if (r0b==3){
      float hv[4];
      if (sub==IPB-1){ CP4(hv, pv3); }
      else {
        int hro = bS + ((y0+16)<<9) + c4o;
        if (c4p){
          float rh[4], ph[4], vh[4];
          LD4(rh, RH+hro); LD4(ph, PHo+hro); LD4(vh, VHo+hro);
          #pragma unroll
          for (int j=0;j<4;++j) hv[j] = rh[j] + beta*(ph[j]-omega*vh[j]);
        } else { LD4(hv, PHo+hro); }
      }
      ST4(&tile[RPB+1][c4o], hv);
    }
    if (c4p){
      if (r0b==0) ST4(PHn+row0o, pv0);
      if (r0b==3) ST4(PHn+row15o, pv3);
    }
    __syncthreads();
    {
      float s1=0.f, s2=0.f, vv0[4], vv3[4];
      #pragma unroll
      for (int k=0;k<4;++k){
        int fy = y0 + r0b + 4*k, st = r0b + 4*k + 1;
        float ax[4], axl, by[4], bym[4];
        load_coefs(CA, CB, bS, fy, c4o, ax, axl, by, bym);
        float zc[4], zu[4], zd[4];
        LD4(zc, &tile[st][c4o]);
        float zl = c4o ? tile[st][c4o-1] : zc[0];
        float zr = (c4o<508) ? tile[st][c4o+4] : zc[3];
        LD4(zu, &tile[st-1][c4o]);
        LD4(zd, &tile[st+1][c4o]);
        float ov[4];
        stencil4(zc, zl, zr, zu, zd, ax, axl, by, bym, ov);
        #pragma unroll
        for (int j=0;j<4;++j){
          v_[k][j]=ov[j]; s1 += ov[j]*r0_[k][j]; s2 += ov[j]*ov[j];
        }
        if (k==0){ CP4(vv0, ov); }
        if (k==3){ CP4(vv3, ov); }
      }
      if (r0b==0) ST4(VHn+row0o, vv0);
      if (r0b==3) ST4(VHn+row15o, vv3);
      store3(aux, s1, s2, 0.f, blk);
    }
    if (c4p) ppar ^= 1;
    vpar ^= 1;
    img_barrier(bar, IPB*(++ep));
    img_red3(aux, img, 2, red);
    float sig = red[0], vabs = sqrtf(red[1]);

    if (sig <= EPSF*vabs*r0abs){
      // ---- restart: p = r = r0 = b - A(x) ----
      float* PHn2 = ws + (size_t)(P_PH0+(ppar^1))*NSF;
      #pragma unroll
      for (int k=0;k<4;++k){ ST4(&tile[r0b+4*k+1][c4o], x_[k]); }
      if (r0b==0){
        float hv[4];
        if (sub==0){ CP4(hv, x_[0]); }
        else { LD4(hv, XH + bS + ((y0-1)<<9) + c4o); }
        ST4(&tile[0][c4o], hv);
      }
      if (r0b==3){
        float hv[4];
        if (sub==IPB-1){ CP4(hv, x_[3]); }
        else { LD4(hv, XH + bS + ((y0+16)<<9) + c4o); }
        ST4(&tile[RPB+1][c4o], hv);
      }
      __syncthreads();
      float pa=0.f, pn0[4], pn3[4];
      #pragma unroll
      for (int k=0;k<4;++k){
        int fy = y0 + r0b + 4*k, st = r0b + 4*k + 1;
        float ax[4], axl, by[4], bym[4];
        load_coefs(CA, CB, bS, fy, c4o, ax, axl, by, bym);
        float zc[4], zu[4], zd[4];
        LD4(zc, &tile[st][c4o]);
        float zl = c4o ? tile[st][c4o-1] : zc[0];
        float zr = (c4o<508) ? tile[st][c4o+4] : zc[3];
        LD4(zu, &tile[st-1][c4o]);
        LD4(zd, &tile[st+1][c4o]);
        float av[4], pn[4];
        stencil4(zc, zl, zr, zu, zd, ax, axl, by, bym, av);
        #pragma unroll
        for (int j=0;j<4;++j){
          pn[j] = c - av[j];
          p_[k][j]=pn[j]; r_[k][j]=pn[j]; r0_[k][j]=pn[j];
          pa += pn[j]*pn[j];
        }
        if (k==0){ CP4(pn0, pn); }
        if (k==3){ CP4(pn3, pn); }
      }
      if (r0b==0){ ST4(PHn2+row0o, pn0); ST4(RH+row0o, pn0); }
      if (r0b==3){ ST4(PHn2+row15o, pn3); ST4(RH+row15o, pn3); }
      ppar ^= 1;
      store3(aux, pa, 0.f, 0.f, blk);
      img_barrier(bar, IPB*(++ep));
      rr0 = img_red1(aux+A_PA, img);
      r0abs = sqrtf(rr0); rabs = r0abs; kcnt++;
      c4p = false;
      continue;
    }

    // ---- P2: s = r - alpha*v (tile); t = A(s); partials ss, ts, tt ----
    alpha = rr0 / sig;
    {
      const float* VHc = ws + (size_t)(P_VH0+vpar)*NSF;   // current v halo
      float ssp=0.f, sv0[4], sv3[4];
      #pragma unroll
      for (int k=0;k<4;++k){
        int st = r0b + 4*k + 1;
        float sv[4];
        #pragma unroll
        for (int j=0;j<4;++j){
          sv[j] = r_[k][j] - alpha*v_[k][j];
          ssp += sv[j]*sv[j];
        }
        ST4(&tile[st][c4o], sv);
        if (k==0){ CP4(sv0, sv); }
        if (k==3){ CP4(sv3, sv); }
      }
      if (r0b==0){
        float hv[4];
        if (sub==0){ CP4(hv, sv0); }
        else {
          int hro = bS + ((y0-1)<<9) + c4o;
          float rh[4], vh[4];
          LD4(rh, RH+hro); LD4(vh, VHc+hro);
          #pragma unroll
          for (int j=0;j<4;++j) hv[j] = rh[j] - alpha*vh[j];
        }
        ST4(&tile[0][c4o], hv);
      }
      if (r0b==3){
        float hv[4];
        if (sub==IPB-1){ CP4(hv, sv3); }
        else {
          int hro = bS + ((y0+16)<<9) + c4o;
          float rh[4], vh[4];
          LD4(rh, RH+hro); LD4(vh, VHc+hro);
          #pragma unroll
          for (int j=0;j<4;++j) hv[j] = rh[j] - alpha*vh[j];
        }
        ST4(&tile[RPB+1][c4o], hv);
      }
      __syncthreads();
      float tsp=0.f, ttp=0.f;
      #pragma unroll
      for (int k=0;k<4;++k){
        int fy = y0 + r0b + 4*k, st = r0b + 4*k + 1;
        float ax[4], axl, by[4], bym[4];
        load_coefs(CA, CB, bS, fy, c4o, ax, axl, by, bym);
        float zc[4], zu[4], zd[4];
        LD4(zc, &tile[st][c4o]);
        float zl = c4o ? tile[st][c4o-1] : zc[0];
        float zr = (c4o<508) ? tile[st][c4o+4] : zc[3];
        LD4(zu, &tile[st-1][c4o]);
        LD4(zd, &tile[st+1][c4o]);
        float tv[4];
        stencil4(zc, zl, zr, zu, zd, ax, axl, by, bym, tv);
        #pragma unroll
        for (int j=0;j<4;++j){
          t_[k][j]=tv[j]; tsp += tv[j]*zc[j]; ttp += tv[j]*tv[j];
        }
      }
      store3(aux, ssp, tsp, ttp, blk);
    }
    img_barrier(bar, IPB*(++ep));
    img_red3(aux, img, 3, red);
    float snorm = sqrtf(red[0]);

    if (snorm <= THR){
      // ---- c3: x += alpha*p; exit (conv false next check) ----
      #pragma unroll
      for (int k=0;k<4;++k)
        #pragma unroll
        for (int j=0;j<4;++j) x_[k][j] += alpha*p_[k][j];
      rabs = snorm; kcnt++; c4p = false;
      continue;
    }

    // ---- c4: x += alpha*p + omega*s; r = s - omega*t ----
    omega = red[1]/red[2];
    {
      float s1=0.f, s2=0.f, rn0[4], rn3[4], xn0[4], xn3[4];
      #pragma unroll
      for (int k=0;k<4;++k){
        int st = r0b + 4*k + 1;
        float sv[4], rn[4], xn[4];
        LD4(sv, &tile[st][c4o]);
        #pragma unroll
        for (int j=0;j<4;++j){
          xn[j] = x_[k][j] + alpha*p_[k][j] + omega*sv[j];
          x_[k][j] = xn[j];
          rn[j] = sv[j] - omega*t_[k][j];
          r_[k][j] = rn[j];
          s1 += rn[j]*r0_[k][j]; s2 += rn[j]*rn[j];
        }
        if (k==0){ CP4(rn0, rn); CP4(xn0, xn); }
        if (k==3){ CP4(rn3, rn); CP4(xn3, xn); }
      }
      if (r0b==0){ ST4(RH+row0o, rn0); ST4(XH+row0o, xn0); }
      if (r0b==3){ ST4(RH+row15o, rn3); ST4(XH+row15o, xn3); }
      store3(aux, s1, s2, 0.f, blk);
    }
    img_barrier(bar, IPB*(++ep));
    img_red3(aux, img, 2, red);
    beta = alpha/omega*(red[0]/rr0);
    rr0 = red[0];
    rabs = sqrtf(fmaxf(red[1], 0.f));
    kcnt++;
    c4p = true;
  }

  // ---- pack: out[img][i][j]: border=c, interior = x[j-1][i-1] ----
  __syncthreads();
  float* lp = &tile[0][0];                  // reused as [16][516]
  #pragma unroll
  for (int k=0;k<4;++k){
    int ri = r0b + 4*k;
    ST4(lp + ri*516 + c4o, x_[k]);
  }
  float* outb = outg + (size_t)img*PADS*PADS;
  if (sub == 0){
    for (int e = tid; e < 2052; e += NT){
      int i, j;
      if (e < 514)      { i=0;        j=e;      }
      else if (e < 1028){ i=513;      j=e-514;  }
      else if (e < 1540){ i=e-1028+1; j=0;      }
      else              { i=e-1540+1; j=513;    }
      outb[i*PADS+j] = c;
    }
  }
  __syncthreads();
  {
    int qq = tid & 15, xb = tid >> 4;       // 16 cols x 32 x-groups
    #pragma unroll
    for (int ps=0; ps<16; ++ps){
      int xc = ps*32 + xb;
      outb[(size_t)(xc+1)*PADS + (y0+1+qq)] = lp[qq*516 + xc];
    }
  }
}

} // namespace

extern "C" void kernel_launch(void* const* d_in, const int* in_sizes, int n_in,
                              void* d_out, int out_size, void* d_ws, size_t ws_size,
                              hipStream_t stream){
  const float* V  = (const float*)d_in[0];
  const float* M1 = (const float*)d_in[1];
  const float* M2 = (const float*)d_in[2];
  const int*   km = (const int*)d_in[3];
  float* ws  = (float*)d_ws;
  float* out = (float*)d_out;

  size_t need = ((size_t)NPL*NSF + 2048)*sizeof(float);
  if (ws_size < need) return;

  // zero the per-image barrier counters (graph-capturable)
  hipMemsetAsync((char*)d_ws + ((size_t)NPL*NSF + A_BAR)*sizeof(float),
                 0, 8*32*sizeof(unsigned), stream);

  solve<<<dim3(NB), dim3(NT), 0, stream>>>(V, M1, M2, km, out, ws);
}

// Round 5
// 721.593 us; speedup vs baseline: 2.3804x; 1.1025x over previous
//
#include <hip/hip_runtime.h>
#include <math.h>

// BiCGStab, 8 independent 512x512 images, single persistent kernel.
// 256 blocks x 512 threads (plain launch; 1 block/CU always resident).
// Block = 16 rows of one image; thread = 4 rows x 4 cols.
// All fields (x,p,r,r0,v,t,s) AND stencil coefficients live in registers;
// global traffic = halo rows + flag-slot reductions only.
// Sync = per-image flag protocol: each block writes partials to its own
// slot + release epoch flag; one wave polls all 32 flags (no atomic RMW).
// Scalars recomputed redundantly per block in fixed order (bit-identical
// across blocks -> uniform branches).

namespace {

constexpr int NIMG = 8;
constexpr int NSd  = 512;
constexpr int S    = NSd*NSd;
constexpr int NSF  = NIMG*S;
constexpr int PADS = 514;
constexpr int NB   = 256;
constexpr int IPB  = 32;     // blocks per image
constexpr int RPB  = 16;     // rows per block
constexpr int NT   = 512;
constexpr float EPSF = 1e-9f;
constexpr float THR  = 1e-9f * 262144.0f;
constexpr float RX_=50.f, RY_=50.f, RXX_=100.f, RYY_=100.f;
constexpr float BOO0 = 1.f + 2.f*(RXX_+RYY_);

// halo planes in ws (full-plane indexing; only 2 rows per 16 touched)
enum { P_PH0=0, P_PH1, P_VH0, P_VH1, P_RH, P_XH, NPL };
constexpr int SLOT_FLOATS = 32;                    // 128 B per slot
constexpr int AUX_FLOATS  = NIMG*2*IPB*SLOT_FLOATS; // 16384 floats (64 KB)

__device__ __forceinline__ int cl(int i){ return i<0?0:(i>NSd-1?NSd-1:i); }

#define LD4(d, p) { float4 _t4 = *reinterpret_cast<const float4*>(p); \
  (d)[0]=_t4.x; (d)[1]=_t4.y; (d)[2]=_t4.z; (d)[3]=_t4.w; }
#define ST4(p, s) { *reinterpret_cast<float4*>(p) = \
  make_float4((s)[0],(s)[1],(s)[2],(s)[3]); }
#define CP4(d, s) { (d)[0]=(s)[0]; (d)[1]=(s)[1]; (d)[2]=(s)[2]; (d)[3]=(s)[3]; }

__device__ __forceinline__ float* slot_ptr(float* aux, int img, unsigned ep, int sub){
  return aux + (size_t)((((img<<1)|(ep&1u))*IPB) + sub)*SLOT_FLOATS;
}

// block-reduce 3 partials (fixed order) -> own slot -> release flag
__device__ __forceinline__ void phase_post(float* aux, int img, int sub, unsigned ep,
                                           float a, float b, float c2){
  #pragma unroll
  for (int o=32;o;o>>=1){ a+=__shfl_xor(a,o); b+=__shfl_xor(b,o); c2+=__shfl_xor(c2,o); }
  __shared__ float sa[8], sb[8], sc[8];
  int w = threadIdx.x>>6;
  if ((threadIdx.x&63)==0){ sa[w]=a; sb[w]=b; sc[w]=c2; }
  __syncthreads();
  if (threadIdx.x==0){
    float ta=0.f, tb=0.f, tc=0.f;
    #pragma unroll
    for (int i=0;i<8;++i){ ta+=sa[i]; tb+=sb[i]; tc+=sc[i]; }
    float* sp = slot_ptr(aux,img,ep,sub);
    sp[0]=ta; sp[1]=tb; sp[2]=tc;
    __hip_atomic_store((unsigned*)sp+3, ep, __ATOMIC_RELEASE, __HIP_MEMORY_SCOPE_AGENT);
  }
}

// wave0 polls the image's 32 flags, reduces slots in fixed order, broadcasts
__device__ __forceinline__ void phase_wait(float* aux, int img, unsigned ep, float out[3]){
  __shared__ float bc[3];
  int tid = threadIdx.x;
  if (tid < 64){
    float* sp = slot_ptr(aux,img,ep,tid&31);
    const unsigned* fp = (const unsigned*)sp + 3;
    unsigned f;
    do { f = __hip_atomic_load(fp, __ATOMIC_RELAXED, __HIP_MEMORY_SCOPE_AGENT); }
    while (!__all((int)(f >= ep)));
    __threadfence();   // acquire: invalidate caches before reading partials
    float a = sp[0], b = sp[1], c2 = sp[2];
    #pragma unroll
    for (int o=16;o;o>>=1){ a+=__shfl_xor(a,o); b+=__shfl_xor(b,o); c2+=__shfl_xor(c2,o); }
    if (tid==0){ bc[0]=a; bc[1]=b; bc[2]=c2; }
  }
  __syncthreads();
  out[0]=bc[0]; out[1]=bc[1]; out[2]=bc[2];
  __syncthreads();
}

// 5-point stencil, center strip from registers; reference summation order
__device__ __forceinline__ void stencil_reg(const float zc[4], float zl, float zr,
    const float zu[4], const float zd[4],
    const float ax[4], float axl, const float by[4], const float bym[4],
    float out[4]){
  #pragma unroll
  for (int j=0;j<4;++j){
    float axm = j ? ax[j-1] : axl;
    float zxm = j ? zc[j-1] : zl;
    float zxp = (j<3) ? zc[j+1] : zr;
    float boo = BOO0 + ax[j] - axm + by[j] - bym[j];
    out[j] = boo*zc[j] + (-RXX_-axm)*zxm + (-RYY_-bym[j])*zu[j]
           + (-RYY_+by[j])*zd[j] + (-RXX_+ax[j])*zxp;
  }
}

__global__ void __launch_bounds__(NT, 2) solve(const float* __restrict__ Vg,
    const float* __restrict__ M1g, const float* __restrict__ M2g,
    const int* __restrict__ kmp, float* __restrict__ outg, float* __restrict__ ws){
  __shared__ float tile[RPB+2][NSd];     // 36864 B; reused as [16][516] at pack
  const int tid = threadIdx.x, blk = blockIdx.x;
  const int img = blk & 7, sub = blk >> 3;
  const int y0 = sub*RPB, bS = img*S;
  const int cg = tid & 127, r0b = tid >> 7, c4o = cg*4;
  const int lane = tid & 63;
  float* PH[2] = { ws + (size_t)P_PH0*NSF, ws + (size_t)P_PH1*NSF };
  float* VH[2] = { ws + (size_t)P_VH0*NSF, ws + (size_t)P_VH1*NSF };
  float* RH = ws + (size_t)P_RH*NSF;
  float* XH = ws + (size_t)P_XH*NSF;
  float* aux = ws + (size_t)NPL*NSF;
  unsigned ep = 0;
  const int kmax = kmp[0];
  int ppar = 0, vpar = 0;
  const int row0o  = bS + (y0<<9) + c4o;
  const int row15o = bS + ((y0+15)<<9) + c4o;
  float red[3];

  // ---- setup: coefficients into REGISTERS + mean partial ----
  float ax_[4][4], axl_[4], by_[4][4], bym_[4][4];
  float msum = 0.f;
  #pragma unroll
  for (int k=0;k<4;++k){
    int fy = y0 + r0b + 4*k, ro = bS + (fy<<9);
    float vc[4], vd[4], vu[4], m1[4], m2[4], m2u[4];
    LD4(vc, Vg+ro+c4o);
    float vr  = Vg[ro + (c4o<508 ? c4o+4 : 511)];
    float vl  = c4o ? Vg[ro+c4o-1]  : vc[0];
    float m1l = c4o ? M1g[ro+c4o-1] : 0.f;
    LD4(vd, Vg + bS + (cl(fy+1)<<9) + c4o);
    LD4(vu, Vg + bS + (cl(fy-1)<<9) + c4o);
    LD4(m1, M1g+ro+c4o);
    LD4(m2, M2g+ro+c4o);
    if (fy > 0){ LD4(m2u, M2g + bS + ((fy-1)<<9) + c4o); }
    else { m2u[0]=0.f; m2u[1]=0.f; m2u[2]=0.f; m2u[3]=0.f; }
    #pragma unroll
    for (int j=0;j<4;++j){
      float vn = (j<3) ? vc[j+1] : vr;
      ax_[k][j]  = RX_*((vn-vc[j])/(0.5f*(vn+vc[j])))*m1[j];
      by_[k][j]  = RY_*((vd[j]-vc[j])/(0.5f*(vd[j]+vc[j])))*m2[j];
      bym_[k][j] = (fy>0) ? RY_*((vc[j]-vu[j])/(0.5f*(vc[j]+vu[j])))*m2u[j] : 0.f;
      msum += vc[j];
    }
    axl_[k] = c4o ? RX_*((vc[0]-vl)/(0.5f*(vc[0]+vl)))*m1l : 0.f;
  }
  ++ep; phase_post(aux,img,sub,ep, msum,0.f,0.f);
  phase_wait(aux,img,ep,red);
  const float c = red[0]*(1.0f/262144.0f);

  // ---- init: x=c, p=r=r0 = b - A(c) = -2c(ax-axm+by-bym) ----
  float x_[4][4], p_[4][4], r_[4][4], r0_[4][4], v_[4][4], t_[4][4];
  {
    float pa = 0.f;
    #pragma unroll
    for (int k=0;k<4;++k){
      #pragma unroll
      for (int j=0;j<4;++j){
        float axm = j ? ax_[k][j-1] : axl_[k];
        float pn = -2.f*c*(ax_[k][j]-axm + by_[k][j]-bym_[k][j]);
        x_[k][j]=c; p_[k][j]=pn; r_[k][j]=pn; r0_[k][j]=pn;
        v_[k][j]=0.f; t_[k][j]=0.f;
        pa += pn*pn;
      }
    }
    if (r0b==0){
      float cc[4]={c,c,c,c};
      ST4(PH[0]+row0o, p_[0]); ST4(RH+row0o, p_[0]); ST4(XH+row0o, cc);
    }
    if (r0b==3){
      float cc[4]={c,c,c,c};
      ST4(PH[0]+row15o, p_[3]); ST4(RH+row15o, p_[3]); ST4(XH+row15o, cc);
    }
    ++ep; phase_post(aux,img,sub,ep, pa,0.f,0.f);
  }
  phase_wait(aux,img,ep,red);
  float rr0 = red[0];
  float r0abs = sqrtf(rr0), rabs = r0abs;
  int kcnt = 0;
  bool c4p = false;
  float alpha=0.f, omega=0.f, beta=0.f;

  for (int it=0; it<kmax; ++it){
    if (!((kcnt < kmax) && (rabs > THR))) break;
    float* PHo = PH[ppar]; float* PHn = PH[ppar^1];
    float* VHo = VH[vpar]; float* VHn = VH[vpar^1];

    // ---- P1: deferred p-update; v = A(p); partials <v,r0>, <v,v> ----
    #pragma unroll
    for (int k=0;k<4;++k){
      if (c4p){
        #pragma unroll
        for (int j=0;j<4;++j)
          p_[k][j] = r_[k][j] + beta*(p_[k][j]-omega*v_[k][j]);
      }
      ST4(&tile[r0b+4*k+1][c4o], p_[k]);
    }
    if (r0b==0){
      float hv[4];
      if (sub==0){ CP4(hv, p_[0]); }
      else {
        int hro = bS + ((y0-1)<<9) + c4o;
        if (c4p){
          float rh[4], ph[4], vh[4];
          LD4(rh, RH+hro); LD4(ph, PHo+hro); LD4(vh, VHo+hro);
          #pragma unroll
          for (int j=0;j<4;++j) hv[j] = rh[j] + beta*(ph[j]-omega*vh[j]);
        } else { LD4(hv, PHo+hro); }
      }
      ST4(&tile[0][c4o], hv);
      if (c4p) ST4(PHn+row0o, p_[0]);
    }
    if (r0b==3){
      float hv[4];
      if (sub==IPB-1){ CP4(hv, p_[3]); }
      else {
        int hro = bS + ((y0+16)<<9) + c4o;
        if (c4p){
          float rh[4], ph[4], vh[4];
          LD4(rh, RH+hro); LD4(ph, PHo+hro); LD4(vh, VHo+hro);
          #pragma unroll
          for (int j=0;j<4;++j) hv[j] = rh[j] + beta*(ph[j]-omega*vh[j]);
        } else { LD4(hv, PHo+hro); }
      }
      ST4(&tile[RPB+1][c4o], hv);
      if (c4p) ST4(PHn+row15o, p_[3]);
    }
    __syncthreads();
    {
      float s1=0.f, s2=0.f;
      #pragma unroll
      for (int k=0;k<4;++k){
        int st = r0b+4*k+1;
        float zu[4], zd[4], ov[4];
        LD4(zu, &tile[st-1][c4o]);
        LD4(zd, &tile[st+1][c4o]);
        float zl = __shfl_up(p_[k][3], 1);
        float zr = __shfl_down(p_[k][0], 1);
        if (lane==0)  zl = (c4o==0)   ? p_[k][0] : tile[st][c4o-1];
        if (lane==63) zr = (c4o==508) ? p_[k][3] : tile[st][c4o+4];
        stencil_reg(p_[k], zl, zr, zu, zd, ax_[k], axl_[k], by_[k], bym_[k], ov);
        #pragma unroll
        for (int j=0;j<4;++j){
          v_[k][j]=ov[j]; s1 += ov[j]*r0_[k][j]; s2 += ov[j]*ov[j];
        }
      }
      if (r0b==0) ST4(VHn+row0o, v_[0]);
      if (r0b==3) ST4(VHn+row15o, v_[3]);
      ++ep; phase_post(aux,img,sub,ep, s1,s2,0.f);
    }
    if (c4p) ppar ^= 1;
    vpar ^= 1;
    phase_wait(aux,img,ep,red);
    float sig = red[0], vabs = sqrtf(red[1]);

    if (sig <= EPSF*vabs*r0abs){
      // ---- restart: p = r = r0 = b - A(x) ----
      float* PHn2 = PH[ppar^1];
      #pragma unroll
      for (int k=0;k<4;++k){ ST4(&tile[r0b+4*k+1][c4o], x_[k]); }
      if (r0b==0){
        float hv[4];
        if (sub==0){ CP4(hv, x_[0]); }
        else { LD4(hv, XH + bS + ((y0-1)<<9) + c4o); }
        ST4(&tile[0][c4o], hv);
      }
      if (r0b==3){
        float hv[4];
        if (sub==IPB-1){ CP4(hv, x_[3]); }
        else { LD4(hv, XH + bS + ((y0+16)<<9) + c4o); }
        ST4(&tile[RPB+1][c4o], hv);
      }
      __syncthreads();
      float pa = 0.f;
      #pragma unroll
      for (int k=0;k<4;++k){
        int st = r0b+4*k+1;
        float zu[4], zd[4], av[4];
        LD4(zu, &tile[st-1][c4o]);
        LD4(zd, &tile[st+1][c4o]);
        float zl = __shfl_up(x_[k][3], 1);
        float zr = __shfl_down(x_[k][0], 1);
        if (lane==0)  zl = (c4o==0)   ? x_[k][0] : tile[st][c4o-1];
        if (lane==63) zr = (c4o==508) ? x_[k][3] : tile[st][c4o+4];
        stencil_reg(x_[k], zl, zr, zu, zd, ax_[k], axl_[k], by_[k], bym_[k], av);
        #pragma unroll
        for (int j=0;j<4;++j){
          float pn = c - av[j];
          p_[k][j]=pn; r_[k][j]=pn; r0_[k][j]=pn;
          pa += pn*pn;
        }
      }
      if (r0b==0){ ST4(PHn2+row0o, p_[0]); ST4(RH+row0o, p_[0]); }
      if (r0b==3){ ST4(PHn2+row15o, p_[3]); ST4(RH+row15o, p_[3]); }
      ppar ^= 1;
      ++ep; phase_post(aux,img,sub,ep, pa,0.f,0.f);
      phase_wait(aux,img,ep,red);
      rr0 = red[0]; r0abs = sqrtf(rr0); rabs = r0abs; kcnt++;
      c4p = false;
      continue;
    }

    // ---- P2: s = r - alpha*v; t = A(s); partials ss, ts, tt ----
    alpha = rr0 / sig;
    float* VHc = VH[vpar];
    float sv_[4][4];
    {
      float ssp = 0.f;
      #pragma unroll
      for (int k=0;k<4;++k){
        #pragma unroll
        for (int j=0;j<4;++j){
          sv_[k][j] = r_[k][j] - alpha*v_[k][j];
          ssp += sv_[k][j]*sv_[k][j];
        }
        ST4(&tile[r0b+4*k+1][c4o], sv_[k]);
      }
      if (r0b==0){
        float hv[4];
        if (sub==0){ CP4(hv, sv_[0]); }
        else {
          int hro = bS + ((y0-1)<<9) + c4o;
          float rh[4], vh[4];
          LD4(rh, RH+hro); LD4(vh, VHc+hro);
          #pragma unroll
          for (int j=0;j<4;++j) hv[j] = rh[j] - alpha*vh[j];
        }
        ST4(&tile[0][c4o], hv);
      }
      if (r0b==3){
        float hv[4];
        if (sub==IPB-1){ CP4(hv, sv_[3]); }
        else {
          int hro = bS + ((y0+16)<<9) + c4o;
          float rh[4], vh[4];
          LD4(rh, RH+hro); LD4(vh, VHc+hro);
          #pragma unroll
          for (int j=0;j<4;++j) hv[j] = rh[j] - alpha*vh[j];
        }
        ST4(&tile[RPB+1][c4o], hv);
      }
      __syncthreads();
      float tsp = 0.f, ttp = 0.f;
      #pragma unroll
      for (int k=0;k<4;++k){
        int st = r0b+4*k+1;
        float zu[4], zd[4], tv[4];
        LD4(zu, &tile[st-1][c4o]);
        LD4(zd, &tile[st+1][c4o]);
        float zl = __shfl_up(sv_[k][3], 1);
        float zr = __shfl_down(sv_[k][0], 1);
        if (lane==0)  zl = (c4o==0)   ? sv_[k][0] : tile[st][c4o-1];
        if (lane==63) zr = (c4o==508) ? sv_[k][3] : tile[st][c4o+4];
        stencil_reg(sv_[k], zl, zr, zu, zd, ax_[k], axl_[k], by_[k], bym_[k], tv);
        #pragma unroll
        for (int j=0;j<4;++j){
          t_[k][j]=tv[j]; tsp += tv[j]*sv_[k][j]; ttp += tv[j]*tv[j];
        }
      }
      ++ep; phase_post(aux,img,sub,ep, ssp,tsp,ttp);
    }
    phase_wait(aux,img,ep,red);
    float snorm = sqrtf(red[0]);

    if (snorm <= THR){
      // ---- c3: x += alpha*p; loop exits on next check ----
      #pragma unroll
      for (int k=0;k<4;++k)
        #pragma unroll
        for (int j=0;j<4;++j) x_[k][j] += alpha*p_[k][j];
      rabs = snorm; kcnt++; c4p = false;
      continue;
    }

    // ---- c4: x += alpha*p + omega*s; r = s - omega*t ----
    omega = red[1]/red[2];
    {
      float s1=0.f, s2=0.f;
      #pragma unroll
      for (int k=0;k<4;++k){
        #pragma unroll
        for (int j=0;j<4;++j){
          x_[k][j] = x_[k][j] + alpha*p_[k][j] + omega*sv_[k][j];
          float rn = sv_[k][j] - omega*t_[k][j];
          r_[k][j] = rn;
          s1 += rn*r0_[k][j]; s2 += rn*rn;
        }
      }
      if (r0b==0){ ST4(RH+row0o, r_[0]); ST4(XH+row0o, x_[0]); }
      if (r0b==3){ ST4(RH+row15o, r_[3]); ST4(XH+row15o, x_[3]); }
      ++ep; phase_post(aux,img,sub,ep, s1,s2,0.f);
    }
    phase_wait(aux,img,ep,red);
    beta = alpha/omega*(red[0]/rr0);
    rr0 = red[0];
    rabs = sqrtf(fmaxf(red[1], 0.f));
    kcnt++;
    c4p = true;
  }

  // ---- pack: out[img][i][j]: border=c, interior = x[j-1][i-1] ----
  __syncthreads();
  float* lp = &tile[0][0];                  // reused as [16][516]
  #pragma unroll
  for (int k=0;k<4;++k){
    int ri = r0b + 4*k;
    ST4(lp + ri*516 + c4o, x_[k]);
  }
  float* outb = outg + (size_t)img*PADS*PADS;
  if (sub == 0){
    for (int e = tid; e < 2052; e += NT){
      int i, j;
      if (e < 514)      { i=0;        j=e;      }
      else if (e < 1028){ i=513;      j=e-514;  }
      else if (e < 1540){ i=e-1028+1; j=0;      }
      else              { i=e-1540+1; j=513;    }
      outb[i*PADS+j] = c;
    }
  }
  __syncthreads();
  {
    int qq = tid & 15, xb = tid >> 4;       // 16 rows x 32 col-groups
    #pragma unroll
    for (int ps=0; ps<16; ++ps){
      int xc = ps*32 + xb;
      outb[(size_t)(xc+1)*PADS + (y0+1+qq)] = lp[qq*516 + xc];
    }
  }
}

} // namespace

extern "C" void kernel_launch(void* const* d_in, const int* in_sizes, int n_in,
                              void* d_out, int out_size, void* d_ws, size_t ws_size,
                              hipStream_t stream){
  const float* V  = (const float*)d_in[0];
  const float* M1 = (const float*)d_in[1];
  const float* M2 = (const float*)d_in[2];
  const int*   km = (const int*)d_in[3];
  float* ws  = (float*)d_ws;
  float* out = (float*)d_out;

  size_t need = ((size_t)NPL*NSF + AUX_FLOATS)*sizeof(float);
  if (ws_size < need) return;

  // zero the flag/slot region each call (graph-capturable)
  hipMemsetAsync((char*)d_ws + (size_t)NPL*NSF*sizeof(float),
                 0, AUX_FLOATS*sizeof(float), stream);

  solve<<<dim3(NB), dim3(NT), 0, stream>>>(V, M1, M2, km, out, ws);
}